// Round 24
// baseline (208.016 us; speedup 1.0000x reference)
//
#include <hip/hip_runtime.h>
#include <hip/hip_fp8.h>

typedef float  f32x4  __attribute__((ext_vector_type(4)));
typedef unsigned short u16;
typedef unsigned int   u32;
typedef unsigned long long u64;

#define BATCH 2048
#define DM    256
#define NFEAT 32768
#define NBLK  8
#define ALPHA_C   0.99f
#define EPS_CTRL  3e-4f
#define TARGET_L0 100.0f

#define BT    32          // batch rows per workgroup
#define FC    2048        // features per chunk
#define NCHUNK (NFEAT / FC)
#define MACRO 128         // features per macro-iter
#define NMACRO (FC / MACRO)
#define NPMAX 24          // max pieces = 16 chunks + 7 seg boundaries
#define ACTS_SZ (BT * MACRO)   // bytes (fp8)

// fp8 pre-scales (keep weights in e4m3 normal range; unscale after MFMA)
#define SCL_WE 8.0f
#define INV_WE 0.125f
#define SCL_WD 16.0f
#define INV_WD 0.0625f

// ---- workspace layout ----
#define WS_RA    0
#define WS_SCALE 1
#define WS_L0    2      // as unsigned
#define WS_L1    4      // 8 floats
#define WS_ERR   16     // 8 floats
#define WSI_BND  32     // 8 ints
#define WSI_PTN  40
#define WSI_PTS  41
#define WSI_PSEG 66
#define WS_WDN   256    // 32768 floats
#define PIECES_OFF_BYTES ((size_t)262144)                         // 256 KB
#define PIECES_BYTES ((size_t)NPMAX * BATCH * DM * 2)             // 24 MB bf16
#define WEP_OFF_BYTES (PIECES_OFF_BYTES + PIECES_BYTES)           // fp8 We, 8 MB
#define WDP_OFF_BYTES (WEP_OFF_BYTES + (size_t)NFEAT * DM)        // fp8 Wd, 8 MB

// lgkm-only barrier (protects LDS only; global loads ride across)
#define RAW_BARRIER() asm volatile("s_waitcnt lgkmcnt(0)\n\ts_barrier" ::: "memory")

static __device__ inline u16 f2b(float f) {
    return __builtin_bit_cast(u16, (__bf16)f);
}
static __device__ inline float b2f(u16 u) {
    return (float)__builtin_bit_cast(__bf16, u);
}
// pack 2 f32 -> 2 fp8(e4m3) in low 16 bits
static __device__ inline u32 f2f8x2(float a, float b) {
#if __has_builtin(__builtin_amdgcn_cvt_pk_fp8_f32)
    return ((u32)__builtin_amdgcn_cvt_pk_fp8_f32(a, b, 0, false)) & 0xFFFFu;
#else
    __hip_fp8_e4m3 ha(a), hb(b);
    return (u32)(*reinterpret_cast<unsigned char*>(&ha)) |
           ((u32)(*reinterpret_cast<unsigned char*>(&hb)) << 8);
#endif
}
static __device__ inline f32x4 mfma8(u64 a, u64 b, f32x4 c) {
    return __builtin_amdgcn_mfma_f32_16x16x32_fp8_fp8((long)a, (long)b, c, 0, 0, 0);
}

// ---------------- merged prep+pack kernel ----------------
// bid < 1024: We fp8 pack slab; bid < 2048: Wd fp8 pack slab + fused wdn;
// bid < 2048+512: x rownorm; else: seg boundary detect. (k_prep merged into
// this grid: independent inputs/outputs, fills pack's tail; one less launch.)
__global__ __launch_bounds__(256) void k_pack(const float* __restrict__ We,
                                              const float* __restrict__ Wd,
                                              const float* __restrict__ x,
                                              const int* __restrict__ seg,
                                              unsigned char* __restrict__ WeP,
                                              unsigned char* __restrict__ WdP,
                                              float* ws) {
    __shared__ float tile[32][261];   // pitch 261: spreads gather banks
    const int t = threadIdx.x;
    const int bid = blockIdx.x;
    if (bid < 1024) {
        const int kf = bid & 7, fblk = bid >> 3;
        const int f0 = fblk * 256;
        #pragma unroll
        for (int p = 0; p < 8; ++p) {
            const int r = p * 4 + (t >> 6);
            const int c = (t & 63) * 4;
            const float4 v = *reinterpret_cast<const float4*>(We + (size_t)(kf * 32 + r) * NFEAT + f0 + c);
            tile[r][c] = v.x; tile[r][c + 1] = v.y; tile[r][c + 2] = v.z; tile[r][c + 3] = v.w;
        }
        __syncthreads();
        #pragma unroll
        for (int p = 0; p < 4; ++p) {
            const int item = p * 256 + t;
            const int g = item >> 6, l = item & 63;
            const int F = fblk * 16 + g;
            float tv[8];
            #pragma unroll
            for (int i = 0; i < 8; ++i)
                tv[i] = tile[(l >> 4) * 8 + i][g * 16 + (l & 15)] * SCL_WE;
            const u32 lo = f2f8x2(tv[0], tv[1]) | (f2f8x2(tv[2], tv[3]) << 16);
            const u32 hi = f2f8x2(tv[4], tv[5]) | (f2f8x2(tv[6], tv[7]) << 16);
            *reinterpret_cast<u64*>(WeP + ((size_t)(F * 8 + kf) * 64 + l) * 8) = (u64)lo | ((u64)hi << 32);
        }
    } else if (bid < 2048) {
        const int G = bid - 1024;
        #pragma unroll
        for (int p = 0; p < 8; ++p) {
            const int r = p * 4 + (t >> 6);
            const int c = (t & 63) * 4;
            const float4 v = *reinterpret_cast<const float4*>(Wd + (size_t)(G * 32 + r) * DM + c);
            tile[r][c] = v.x; tile[r][c + 1] = v.y; tile[r][c + 2] = v.z; tile[r][c + 3] = v.w;
        }
        __syncthreads();
        // fused wdn (from f32 tile — unaffected by fp8 scaling)
        {
            const int row = t >> 3, part = t & 7;
            float s = 0.0f;
            #pragma unroll
            for (int j = 0; j < 32; ++j) {
                const float xv = tile[row][part * 32 + j];
                s += xv * xv;
            }
            s += __shfl_xor(s, 1); s += __shfl_xor(s, 2); s += __shfl_xor(s, 4);
            if (part == 0) ws[WS_WDN + G * 32 + row] = sqrtf(s);
        }
        #pragma unroll
        for (int p = 0; p < 4; ++p) {
            const int item = p * 256 + t;
            const int g = item >> 6, l = item & 63;
            float tv[8];
            #pragma unroll
            for (int i = 0; i < 8; ++i)
                tv[i] = tile[(l >> 4) * 8 + i][g * 16 + (l & 15)] * SCL_WD;
            const u32 lo = f2f8x2(tv[0], tv[1]) | (f2f8x2(tv[2], tv[3]) << 16);
            const u32 hi = f2f8x2(tv[4], tv[5]) | (f2f8x2(tv[6], tv[7]) << 16);
            *reinterpret_cast<u64*>(WdP + ((size_t)(g * 1024 + G) * 64 + l) * 8) = (u64)lo | ((u64)hi << 32);
        }
    } else if (bid < 2048 + BATCH / 4) {
        // x rownorm (was k_prep role 1)
        const int wave = t >> 6, lane = t & 63;
        const int row = (bid - 2048) * 4 + wave;
        const float4 v = *reinterpret_cast<const float4*>(x + (size_t)row * DM + lane * 4);
        float s = v.x * v.x + v.y * v.y + v.z * v.z + v.w * v.w;
        #pragma unroll
        for (int o = 32; o; o >>= 1) s += __shfl_xor(s, o);
        if (lane == 0) atomicAdd(&ws[WS_RA], sqrtf(s));
    } else {
        // seg boundaries (was k_prep role 2)
        const int f = (bid - 2048 - BATCH / 4) * 256 + t;
        if (f > 0 && f < NFEAT) {
            const int s = seg[f];
            if (s != seg[f - 1]) ((int*)ws)[WSI_BND + s] = f;
        }
    }
}

// piece table + normalizer scale; 64 threads
__global__ void k_pt2(const int* __restrict__ seg,
                      const float* __restrict__ ravg, float* ws) {
    __shared__ int stv[NCHUNK + NBLK];
    __shared__ int outL[NPMAX];
    __shared__ int NL;
    int* wsi = (int*)ws;
    const int t = threadIdx.x;
    if (t < NCHUNK) stv[t] = t * FC;
    else if (t < NCHUNK + NBLK - 1) stv[t] = wsi[WSI_BND + (t - NCHUNK + 1)];
    __syncthreads();
    if (t == 0) {
        int i = 0, j = NCHUNK, N = 0;
        while (i < NCHUNK || j < NCHUNK + NBLK - 1) {
            int v;
            if (i < NCHUNK && (j >= NCHUNK + NBLK - 1 || stv[i] <= stv[j])) v = stv[i++];
            else v = stv[j++];
            if (N == 0 || outL[N - 1] != v) outL[N++] = v;
        }
        NL = N;
    }
    __syncthreads();
    const int N = NL;
    if (t < N) {
        wsi[WSI_PTS + t] = outL[t];
        wsi[WSI_PSEG + t] = seg[outL[t]];
    }
    if (t == 0) {
        wsi[WSI_PTN] = N;
        wsi[WSI_PTS + N] = NFEAT;
        float ra = ALPHA_C * ravg[0] + (1.0f - ALPHA_C) * (ws[WS_RA] / (float)BATCH);
        ws[WS_SCALE] = 16.0f / ra;   // sqrt(256) = 16
    }
}

// ---------------- fused main kernel: r19 verified optimum, unchanged ----------------
// 256 threads = 4 waves, BT=32, MACRO=128: in-iteration branchless burst
// (We(it)+Wd(it-1)), enc -> dec -> epi, lgkm-only barriers, fp8-e4m3 operands
// (weights L2-resident: FETCH 22 MB). Ledger: (256,1)=254us, rotation=158us,
// bf16=162us, this=143us — measured optimum.
__global__ __launch_bounds__(256, 2) void k_main(const float* __restrict__ x,
                                                 const float* __restrict__ be,
                                                 const int* __restrict__ seg,
                                                 float* __restrict__ ws,
                                                 u16* __restrict__ pieces,
                                                 const unsigned char* __restrict__ WeP,
                                                 const unsigned char* __restrict__ WdP) {
    __shared__ __align__(16) unsigned char xs[BT * DM];        // 8 KB fp8 packed
    __shared__ __align__(16) unsigned char acts[2 * ACTS_SZ];  // 8 KB dbuf fp8
    __shared__ int segL[FC];                                   // 8 KB
    __shared__ float lds_l1[NBLK];
    __shared__ unsigned lds_l0;
    __shared__ int s2s[NBLK];
    __shared__ int msegL[NMACRO];
    __shared__ int muniL[NMACRO];

    const int t = threadIdx.x;
    const int w = t >> 6;           // 0..3
    const int l = t & 63;
    const int l15 = l & 15, lg = l >> 4;
    const int f0 = blockIdx.x * FC;
    const int b0 = blockIdx.y * BT;
    const float scale = ws[WS_SCALE];
    const int* wsi = (const int*)ws;

    if (t < NBLK) lds_l1[t] = 0.0f;
    if (t == 0) lds_l0 = 0u;
    if (t < NPMAX) {
        const int N = wsi[WSI_PTN];
        if (t < N) {
            const int ps = wsi[WSI_PTS + t];
            if (ps >= f0 && ps < f0 + FC) s2s[wsi[WSI_PSEG + t]] = t;
        }
    }

    // stage seg chunk
    #pragma unroll
    for (int p = 0; p < 2; ++p)
        reinterpret_cast<int4*>(segL)[t + p * 256] =
            reinterpret_cast<const int4*>(seg + f0)[t + p * 256];

    // stage xn = x*scale, packed fp8 (32 rows x 256 cols)
    #pragma unroll
    for (int p = 0; p < 8; ++p) {
        const int row = p * 4 + (t >> 6);
        const int col = (t & 63) * 4;
        const float4 v = *reinterpret_cast<const float4*>(x + (size_t)(b0 + row) * DM + col);
        const u32 w01 = f2f8x2(v.x * scale, v.y * scale);
        const u32 w23 = f2f8x2(v.z * scale, v.w * scale);
        const int e = (((row >> 4) * 8 + (col >> 5)) * 512 + ((col >> 3) & 3) * 128 + (row & 15) * 8 + (col & 7));
        *reinterpret_cast<u32*>(&xs[e]) = w01 | (w23 << 16);
    }
    __syncthreads();
    if (t < NMACRO) {
        msegL[t] = segL[t * MACRO];
        muniL[t] = (segL[t * MACRO] == segL[t * MACRO + MACRO - 1]);
    }
    __syncthreads();

    f32x4 pacc[2][4];
    #pragma unroll
    for (int i = 0; i < 2; ++i)
        #pragma unroll
        for (int j = 0; j < 4; ++j) pacc[i][j] = (f32x4)0.0f;

    int cur = msegL[0];
    float l1a0 = 0.0f, l1a1 = 0.0f;
    int myseg = -1;
    unsigned l0c = 0u;
    const int Dg0 = 4 * w;

    auto flush = [&](int s) {
        u16* pb = pieces + (size_t)s2s[s] * (BATCH * DM);
        #pragma unroll
        for (int rt = 0; rt < 2; ++rt)
            #pragma unroll
            for (int ct = 0; ct < 4; ++ct)
                #pragma unroll
                for (int r = 0; r < 4; ++r) {
                    const int row = b0 + 16 * rt + lg * 4 + r;
                    const int col = 64 * w + 16 * ct + l15;
                    pb[(size_t)row * DM + col] = f2b(pacc[rt][ct][r] * INV_WD);
                    pacc[rt][ct][r] = 0.0f;
                }
    };

    // encode MFMAs from pre-loaded We regs
    auto encodeR = [&](f32x4 (&eacc)[2][2], u64 (&we)[2][8]) {
        #pragma unroll
        for (int kf = 0; kf < 8; ++kf) {
            u64 a[2];
            #pragma unroll
            for (int rt = 0; rt < 2; ++rt)
                a[rt] = *reinterpret_cast<const u64*>(&xs[((rt * 8 + kf) * 64 + l) * 8]);
            #pragma unroll
            for (int rt = 0; rt < 2; ++rt)
                #pragma unroll
                for (int ct = 0; ct < 2; ++ct)
                    eacc[rt][ct] = mfma8(a[rt], we[ct][kf], eacc[rt][ct]);
        }
    };

    // epilogue: bias (unscale We), relu, l1/l0, acts -> buf[it&1] as fp8
    auto epilogue = [&](int it, f32x4 (&eacc)[2][2], const float* biasv, const float* wdnv) {
        const bool uni = (muniL[it] != 0);
        unsigned char* ab = acts + (it & 1) * ACTS_SZ;
        const int fbl = it * MACRO;
        #pragma unroll
        for (int ct = 0; ct < 2; ++ct) {
            const int s = uni ? msegL[it] : segL[fbl + 32 * w + 16 * ct + l15];
            if (s != myseg) {
                if (myseg >= 0) atomicAdd(&lds_l1[myseg], l1a0 + l1a1);
                l1a0 = 0.0f; l1a1 = 0.0f; myseg = s;
            }
            #pragma unroll
            for (int rt = 0; rt < 2; ++rt) {
                float av[4];
                #pragma unroll
                for (int r = 0; r < 4; ++r) {
                    float a = fmaf(eacc[rt][ct][r], INV_WE, biasv[ct]);
                    a = fmaxf(a, 0.0f);
                    l0c += (unsigned)__popcll(__ballot(a > 0.0f));
                    if (rt == 0) l1a0 += __logf(fmaf(a, wdnv[ct], 1.0f));
                    else         l1a1 += __logf(fmaf(a, wdnv[ct], 1.0f));
                    av[r] = a;
                }
                const u32 p01 = f2f8x2(av[0], av[1]);
                const u32 p23 = f2f8x2(av[2], av[3]);
                const int e0 = (rt * 4 + w) * 512 + (2 * ct + (l15 >> 3)) * 128 + (lg * 4) * 8 + (l15 & 7);
                ab[e0]      = (unsigned char)(p01 & 0xFF);
                ab[e0 + 8]  = (unsigned char)((p01 >> 8) & 0xFF);
                ab[e0 + 16] = (unsigned char)(p23 & 0xFF);
                ab[e0 + 24] = (unsigned char)((p23 >> 8) & 0xFF);
            }
        }
    };

    // decode macro ms from acts buf[ms&1], B from pre-loaded regs
    auto decodeR = [&](int ms, u64 (&wdv)[4][4]) {
        const unsigned char* ab = acts + (ms & 1) * ACTS_SZ;
        if (muniL[ms]) {
            const int s = msegL[ms];
            if (s != cur) { flush(cur); cur = s; }
            #pragma unroll
            for (int kf = 0; kf < 4; ++kf) {
                u64 a[2];
                #pragma unroll
                for (int rt = 0; rt < 2; ++rt)
                    a[rt] = *reinterpret_cast<const u64*>(&ab[((rt * 4 + kf) * 64 + l) * 8]);
                #pragma unroll
                for (int rt = 0; rt < 2; ++rt)
                    #pragma unroll
                    for (int ct = 0; ct < 4; ++ct)
                        pacc[rt][ct] = mfma8(a[rt], wdv[ct][kf], pacc[rt][ct]);
            }
        } else {
            const int fbl = ms * MACRO;
            #pragma unroll
            for (int kf = 0; kf < 4; ++kf) {
                const int W0 = fbl + kf * 32;
                const int s0 = segL[W0], s1 = segL[W0 + 31];
                if (s0 == s1) {
                    if (s0 != cur) { flush(cur); cur = s0; }
                    u64 a[2];
                    #pragma unroll
                    for (int rt = 0; rt < 2; ++rt)
                        a[rt] = *reinterpret_cast<const u64*>(&ab[((rt * 4 + kf) * 64 + l) * 8]);
                    #pragma unroll
                    for (int rt = 0; rt < 2; ++rt)
                        #pragma unroll
                        for (int ct = 0; ct < 4; ++ct)
                            pacc[rt][ct] = mfma8(a[rt], wdv[ct][kf], pacc[rt][ct]);
                } else {
                    int lo = 0;
                    while (lo < 32) {
                        const int s = segL[W0 + lo];
                        int hi = lo + 1;
                        while (hi < 32 && segL[W0 + hi] == s) ++hi;
                        if (s != cur) { flush(cur); cur = s; }
                        // byte-mask this lane's k-range [lo,hi): lane covers lg*8..lg*8+8
                        const int loB = min(max(lo - lg * 8, 0), 8);
                        const int hiB = min(max(hi - lg * 8, 0), 8);
                        const int n = hiB - loB;
                        u64 mask = 0;
                        if (n >= 8) mask = ~0ull;
                        else if (n > 0) mask = ((1ull << (n * 8)) - 1ull) << (loB * 8);
                        #pragma unroll
                        for (int rt = 0; rt < 2; ++rt) {
                            const u64 a = (*reinterpret_cast<const u64*>(&ab[((rt * 4 + kf) * 64 + l) * 8])) & mask;
                            #pragma unroll
                            for (int ct = 0; ct < 4; ++ct)
                                pacc[rt][ct] = mfma8(a, wdv[ct][kf], pacc[rt][ct]);
                        }
                        lo = hi;
                    }
                }
            }
        }
    };

    // ---- prologue: encode(0) + epilogue(0) ----
    {
        u64 we[2][8];
        const int F0 = (f0 >> 4) + 2 * w;
        #pragma unroll
        for (int kf = 0; kf < 8; ++kf)
            #pragma unroll
            for (int ct = 0; ct < 2; ++ct)
                we[ct][kf] = *reinterpret_cast<const u64*>(WeP + (((size_t)(F0 + ct) * 8 + kf) * 64 + l) * 8);
        float biasv[2], wdnv[2];
        #pragma unroll
        for (int ct = 0; ct < 2; ++ct) {
            const int fg = f0 + 32 * w + 16 * ct + l15;
            biasv[ct] = be[fg];
            wdnv[ct] = ws[WS_WDN + fg] * 10.0f;
        }
        f32x4 eacc[2][2];
        #pragma unroll
        for (int i = 0; i < 2; ++i)
            #pragma unroll
            for (int j = 0; j < 2; ++j) eacc[i][j] = (f32x4)0.0f;
        encodeR(eacc, we);
        epilogue(0, eacc, biasv, wdnv);
    }

    // ---- pipelined main loop: encode(it) || decode(it-1) ----
    for (int it = 1; it <= NMACRO; ++it) {
        RAW_BARRIER();   // acts buf[(it-1)&1] visible; prior reads of buf[it&1] done
        const int itm1 = it - 1;

        if (it < NMACRO) {
            // branchless load burst: We(it) then Wd(it-1) then scalars
            u64 we[2][8];
            const int F0 = ((f0 + it * MACRO) >> 4) + 2 * w;
            #pragma unroll
            for (int kf = 0; kf < 8; ++kf)
                #pragma unroll
                for (int ct = 0; ct < 2; ++ct)
                    we[ct][kf] = *reinterpret_cast<const u64*>(WeP + (((size_t)(F0 + ct) * 8 + kf) * 64 + l) * 8);
            u64 wdv[4][4];
            const int G0 = (f0 + itm1 * MACRO) >> 5;
            #pragma unroll
            for (int kf = 0; kf < 4; ++kf)
                #pragma unroll
                for (int ct = 0; ct < 4; ++ct)
                    wdv[ct][kf] = *reinterpret_cast<const u64*>(WdP + (((size_t)(Dg0 + ct) * 1024 + G0 + kf) * 64 + l) * 8);
            float biasv[2], wdnv[2];
            #pragma unroll
            for (int ct = 0; ct < 2; ++ct) {
                const int fg = f0 + it * MACRO + 32 * w + 16 * ct + l15;
                biasv[ct] = be[fg];
                wdnv[ct] = ws[WS_WDN + fg] * 10.0f;
            }

            f32x4 eacc[2][2];
            #pragma unroll
            for (int i = 0; i < 2; ++i)
                #pragma unroll
                for (int j = 0; j < 2; ++j) eacc[i][j] = (f32x4)0.0f;
            encodeR(eacc, we);          // consumes earliest burst loads
            decodeR(itm1, wdv);         // wd landed during encode
            epilogue(it, eacc, biasv, wdnv);
        } else {
            // drain: decode(NMACRO-1) only
            u64 wdv[4][4];
            const int G0 = (f0 + itm1 * MACRO) >> 5;
            #pragma unroll
            for (int kf = 0; kf < 4; ++kf)
                #pragma unroll
                for (int ct = 0; ct < 4; ++ct)
                    wdv[ct][kf] = *reinterpret_cast<const u64*>(WdP + (((size_t)(Dg0 + ct) * 1024 + G0 + kf) * 64 + l) * 8);
            decodeR(itm1, wdv);
        }
    }

    flush(cur);
    if (myseg >= 0) atomicAdd(&lds_l1[myseg], l1a0 + l1a1);
    if (l == 0) atomicAdd(&lds_l0, l0c);    // l0c wave-uniform (ballot)
    __syncthreads();
    if (t < NBLK) atomicAdd(&ws[WS_L1 + t], lds_l1[t]);
    if (t == 0) atomicAdd(((unsigned*)ws) + WS_L0, lds_l0);
}

// ---------------- epilogue kernels ----------------

__global__ __launch_bounds__(256) void k_err(const float* __restrict__ x,
                                             const float* __restrict__ bd,
                                             float* ws,
                                             const u16* __restrict__ pieces) {
    const int b = blockIdx.x, t = threadIdx.x;
    const int wave = t >> 6, lane = t & 63;
    const int* wsi = (const int*)ws;
    const int N = wsi[WSI_PTN];
    const float scale = ws[WS_SCALE];
    const float xv = x[(size_t)b * DM + t] * scale;
    float p = bd[t];
    __shared__ float lds[NBLK][4];
    for (int i = 0; i < N; ++i) {
        p += b2f(pieces[(size_t)i * (BATCH * DM) + (size_t)b * DM + t]);
        const int sg = wsi[WSI_PSEG + i];
        const bool end = (i == N - 1) || (wsi[WSI_PSEG + i + 1] != sg);
        if (end) {
            const float d = p - xv;
            float e = d * d;
            #pragma unroll
            for (int o = 32; o; o >>= 1) e += __shfl_xor(e, o);
            if (lane == 0) lds[sg][wave] = e;
        }
    }
    __syncthreads();
    if (t < NBLK) {
        const float s = lds[t][0] + lds[t][1] + lds[t][2] + lds[t][3];
        atomicAdd(&ws[WS_ERR + t], s);
    }
}

__global__ void k_loss(const float* __restrict__ bw,
                       const float* __restrict__ l1s,
                       const float* ws, float* out) {
    float cum = 0.0f, l1 = 0.0f, mse = 0.0f;
    for (int k = 0; k < NBLK; ++k) {
        cum += ws[WS_L1 + k] / (float)BATCH;
        l1 += bw[k] * cum;
        mse += bw[k] * (ws[WS_ERR + k] / (float)BATCH);
    }
    l1 *= (1.0f / NBLK);
    mse *= (1.0f / NBLK);
    const unsigned l0 = ((const unsigned*)ws)[WS_L0];
    const float avg_l0 = (float)l0 / (float)BATCH;
    const float rs = l1s[0] * (avg_l0 < TARGET_L0 ? (1.0f - EPS_CTRL) : (1.0f + EPS_CTRL));
    out[0] = mse + rs * l1;
}

// ---------------- launch ----------------

extern "C" void kernel_launch(void* const* d_in, const int* in_sizes, int n_in,
                              void* d_out, int out_size, void* d_ws, size_t ws_size,
                              hipStream_t stream) {
    const float* x    = (const float*)d_in[0];
    const float* We   = (const float*)d_in[1];
    const float* be   = (const float*)d_in[2];
    const float* Wd   = (const float*)d_in[3];
    const float* bd   = (const float*)d_in[4];
    const float* bw   = (const float*)d_in[5];
    const float* ravg = (const float*)d_in[6];
    const float* l1s  = (const float*)d_in[7];
    const int*   seg  = (const int*)d_in[8];
    float* out = (float*)d_out;
    float* ws  = (float*)d_ws;
    u16* pieces = (u16*)((char*)d_ws + PIECES_OFF_BYTES);
    unsigned char* WeP = (unsigned char*)d_ws + WEP_OFF_BYTES;
    unsigned char* WdP = (unsigned char*)d_ws + WDP_OFF_BYTES;

    hipMemsetAsync(d_ws, 0, 1024, stream);           // zero accumulators only
    k_pack<<<2048 + BATCH / 4 + NFEAT / 256, 256, 0, stream>>>(We, Wd, x, seg, WeP, WdP, ws);
    k_pt2<<<1, 64, 0, stream>>>(seg, ravg, ws);
    dim3 g(NFEAT / FC, BATCH / BT);   // chunk-fast -> XCD = chunk%8 (L2-fit weights)
    k_main<<<g, 256, 0, stream>>>(x, be, seg, ws, pieces, WeP, WdP);
    k_err<<<BATCH, 256, 0, stream>>>(x, bd, ws, pieces);
    k_loss<<<1, 1, 0, stream>>>(bw, l1s, ws, out);
}

// Round 25
// 201.018 us; speedup vs baseline: 1.0348x; 1.0348x over previous
//
#include <hip/hip_runtime.h>
#include <hip/hip_fp8.h>

typedef float  f32x4  __attribute__((ext_vector_type(4)));
typedef unsigned short u16;
typedef unsigned int   u32;
typedef unsigned long long u64;

#define BATCH 2048
#define DM    256
#define NFEAT 32768
#define NBLK  8
#define ALPHA_C   0.99f
#define EPS_CTRL  3e-4f
#define TARGET_L0 100.0f

#define BT    32          // batch rows per workgroup
#define FC    2048        // features per chunk
#define NCHUNK (NFEAT / FC)
#define MACRO 128         // features per macro-iter
#define NMACRO (FC / MACRO)
#define NPMAX 24          // max pieces = 16 chunks + 7 seg boundaries
#define ACTS_SZ (BT * MACRO)   // bytes (fp8)

// fp8 pre-scales (keep weights in e4m3 normal range; unscale after MFMA)
#define SCL_WE 8.0f
#define INV_WE 0.125f
#define SCL_WD 16.0f
#define INV_WD 0.0625f

// ---- workspace layout ----
#define WS_RA    0
#define WS_SCALE 1
#define WS_L0    2      // as unsigned
#define WS_L1    4      // 8 floats
#define WS_ERR   16     // 8 floats
#define WSI_BND  32     // 8 ints
#define WSI_PTN  40
#define WSI_PTS  41
#define WSI_PSEG 66
#define WS_WDN   256    // 32768 floats
#define PIECES_OFF_BYTES ((size_t)262144)                         // 256 KB
#define PIECES_BYTES ((size_t)NPMAX * BATCH * DM * 2)             // 24 MB bf16
#define WEP_OFF_BYTES (PIECES_OFF_BYTES + PIECES_BYTES)           // fp8 We, 8 MB
#define WDP_OFF_BYTES (WEP_OFF_BYTES + (size_t)NFEAT * DM)        // fp8 Wd, 8 MB

// lgkm-only barrier (protects LDS only; global loads ride across)
#define RAW_BARRIER() asm volatile("s_waitcnt lgkmcnt(0)\n\ts_barrier" ::: "memory")

static __device__ inline u16 f2b(float f) {
    return __builtin_bit_cast(u16, (__bf16)f);
}
static __device__ inline float b2f(u16 u) {
    return (float)__builtin_bit_cast(__bf16, u);
}
// pack 2 f32 -> 2 fp8(e4m3) in low 16 bits
static __device__ inline u32 f2f8x2(float a, float b) {
#if __has_builtin(__builtin_amdgcn_cvt_pk_fp8_f32)
    return ((u32)__builtin_amdgcn_cvt_pk_fp8_f32(a, b, 0, false)) & 0xFFFFu;
#else
    __hip_fp8_e4m3 ha(a), hb(b);
    return (u32)(*reinterpret_cast<unsigned char*>(&ha)) |
           ((u32)(*reinterpret_cast<unsigned char*>(&hb)) << 8);
#endif
}
static __device__ inline f32x4 mfma8(u64 a, u64 b, f32x4 c) {
    return __builtin_amdgcn_mfma_f32_16x16x32_fp8_fp8((long)a, (long)b, c, 0, 0, 0);
}

// ---------------- merged prep+pack kernel ----------------
// bid < 1024: We fp8 pack slab; bid < 2048: Wd fp8 pack slab + fused wdn;
// bid < 2048+512: x rownorm; else: seg boundary detect.
__global__ __launch_bounds__(256) void k_pack(const float* __restrict__ We,
                                              const float* __restrict__ Wd,
                                              const float* __restrict__ x,
                                              const int* __restrict__ seg,
                                              unsigned char* __restrict__ WeP,
                                              unsigned char* __restrict__ WdP,
                                              float* ws) {
    __shared__ float tile[32][261];   // pitch 261: spreads gather banks
    const int t = threadIdx.x;
    const int bid = blockIdx.x;
    if (bid < 1024) {
        const int kf = bid & 7, fblk = bid >> 3;
        const int f0 = fblk * 256;
        #pragma unroll
        for (int p = 0; p < 8; ++p) {
            const int r = p * 4 + (t >> 6);
            const int c = (t & 63) * 4;
            const float4 v = *reinterpret_cast<const float4*>(We + (size_t)(kf * 32 + r) * NFEAT + f0 + c);
            tile[r][c] = v.x; tile[r][c + 1] = v.y; tile[r][c + 2] = v.z; tile[r][c + 3] = v.w;
        }
        __syncthreads();
        #pragma unroll
        for (int p = 0; p < 4; ++p) {
            const int item = p * 256 + t;
            const int g = item >> 6, l = item & 63;
            const int F = fblk * 16 + g;
            float tv[8];
            #pragma unroll
            for (int i = 0; i < 8; ++i)
                tv[i] = tile[(l >> 4) * 8 + i][g * 16 + (l & 15)] * SCL_WE;
            const u32 lo = f2f8x2(tv[0], tv[1]) | (f2f8x2(tv[2], tv[3]) << 16);
            const u32 hi = f2f8x2(tv[4], tv[5]) | (f2f8x2(tv[6], tv[7]) << 16);
            *reinterpret_cast<u64*>(WeP + ((size_t)(F * 8 + kf) * 64 + l) * 8) = (u64)lo | ((u64)hi << 32);
        }
    } else if (bid < 2048) {
        const int G = bid - 1024;
        #pragma unroll
        for (int p = 0; p < 8; ++p) {
            const int r = p * 4 + (t >> 6);
            const int c = (t & 63) * 4;
            const float4 v = *reinterpret_cast<const float4*>(Wd + (size_t)(G * 32 + r) * DM + c);
            tile[r][c] = v.x; tile[r][c + 1] = v.y; tile[r][c + 2] = v.z; tile[r][c + 3] = v.w;
        }
        __syncthreads();
        // fused wdn (from f32 tile — unaffected by fp8 scaling)
        {
            const int row = t >> 3, part = t & 7;
            float s = 0.0f;
            #pragma unroll
            for (int j = 0; j < 32; ++j) {
                const float xv = tile[row][part * 32 + j];
                s += xv * xv;
            }
            s += __shfl_xor(s, 1); s += __shfl_xor(s, 2); s += __shfl_xor(s, 4);
            if (part == 0) ws[WS_WDN + G * 32 + row] = sqrtf(s);
        }
        #pragma unroll
        for (int p = 0; p < 4; ++p) {
            const int item = p * 256 + t;
            const int g = item >> 6, l = item & 63;
            float tv[8];
            #pragma unroll
            for (int i = 0; i < 8; ++i)
                tv[i] = tile[(l >> 4) * 8 + i][g * 16 + (l & 15)] * SCL_WD;
            const u32 lo = f2f8x2(tv[0], tv[1]) | (f2f8x2(tv[2], tv[3]) << 16);
            const u32 hi = f2f8x2(tv[4], tv[5]) | (f2f8x2(tv[6], tv[7]) << 16);
            *reinterpret_cast<u64*>(WdP + ((size_t)(g * 1024 + G) * 64 + l) * 8) = (u64)lo | ((u64)hi << 32);
        }
    } else if (bid < 2048 + BATCH / 4) {
        // x rownorm
        const int wave = t >> 6, lane = t & 63;
        const int row = (bid - 2048) * 4 + wave;
        const float4 v = *reinterpret_cast<const float4*>(x + (size_t)row * DM + lane * 4);
        float s = v.x * v.x + v.y * v.y + v.z * v.z + v.w * v.w;
        #pragma unroll
        for (int o = 32; o; o >>= 1) s += __shfl_xor(s, o);
        if (lane == 0) atomicAdd(&ws[WS_RA], sqrtf(s));
    } else {
        // seg boundaries
        const int f = (bid - 2048 - BATCH / 4) * 256 + t;
        if (f > 0 && f < NFEAT) {
            const int s = seg[f];
            if (s != seg[f - 1]) ((int*)ws)[WSI_BND + s] = f;
        }
    }
}

// piece table + normalizer scale; 64 threads
__global__ void k_pt2(const int* __restrict__ seg,
                      const float* __restrict__ ravg, float* ws) {
    __shared__ int stv[NCHUNK + NBLK];
    __shared__ int outL[NPMAX];
    __shared__ int NL;
    int* wsi = (int*)ws;
    const int t = threadIdx.x;
    if (t < NCHUNK) stv[t] = t * FC;
    else if (t < NCHUNK + NBLK - 1) stv[t] = wsi[WSI_BND + (t - NCHUNK + 1)];
    __syncthreads();
    if (t == 0) {
        int i = 0, j = NCHUNK, N = 0;
        while (i < NCHUNK || j < NCHUNK + NBLK - 1) {
            int v;
            if (i < NCHUNK && (j >= NCHUNK + NBLK - 1 || stv[i] <= stv[j])) v = stv[i++];
            else v = stv[j++];
            if (N == 0 || outL[N - 1] != v) outL[N++] = v;
        }
        NL = N;
    }
    __syncthreads();
    const int N = NL;
    if (t < N) {
        wsi[WSI_PTS + t] = outL[t];
        wsi[WSI_PSEG + t] = seg[outL[t]];
    }
    if (t == 0) {
        wsi[WSI_PTN] = N;
        wsi[WSI_PTS + N] = NFEAT;
        float ra = ALPHA_C * ravg[0] + (1.0f - ALPHA_C) * (ws[WS_RA] / (float)BATCH);
        ws[WS_SCALE] = 16.0f / ra;   // sqrt(256) = 16
    }
}

// ---------------- fused main kernel: r19 optimum + batched-log epilogue ----------------
// 256 threads = 4 waves, BT=32, MACRO=128. SINGLE CHANGE vs the 4x-verified
// 143us build: the epilogue's 16 logf/macro become 4 via sum(log v) =
// log(prod v) over each (ct,rt) group of 4. v = a*wdn10+1 in [1,~50] so the
// 4-product <= ~6e6: no overflow, f32-exact enough (absmax budget 91.5,
// current 32). Everything else byte-identical.
__global__ __launch_bounds__(256, 2) void k_main(const float* __restrict__ x,
                                                 const float* __restrict__ be,
                                                 const int* __restrict__ seg,
                                                 float* __restrict__ ws,
                                                 u16* __restrict__ pieces,
                                                 const unsigned char* __restrict__ WeP,
                                                 const unsigned char* __restrict__ WdP) {
    __shared__ __align__(16) unsigned char xs[BT * DM];        // 8 KB fp8 packed
    __shared__ __align__(16) unsigned char acts[2 * ACTS_SZ];  // 8 KB dbuf fp8
    __shared__ int segL[FC];                                   // 8 KB
    __shared__ float lds_l1[NBLK];
    __shared__ unsigned lds_l0;
    __shared__ int s2s[NBLK];
    __shared__ int msegL[NMACRO];
    __shared__ int muniL[NMACRO];

    const int t = threadIdx.x;
    const int w = t >> 6;           // 0..3
    const int l = t & 63;
    const int l15 = l & 15, lg = l >> 4;
    const int f0 = blockIdx.x * FC;
    const int b0 = blockIdx.y * BT;
    const float scale = ws[WS_SCALE];
    const int* wsi = (const int*)ws;

    if (t < NBLK) lds_l1[t] = 0.0f;
    if (t == 0) lds_l0 = 0u;
    if (t < NPMAX) {
        const int N = wsi[WSI_PTN];
        if (t < N) {
            const int ps = wsi[WSI_PTS + t];
            if (ps >= f0 && ps < f0 + FC) s2s[wsi[WSI_PSEG + t]] = t;
        }
    }

    // stage seg chunk
    #pragma unroll
    for (int p = 0; p < 2; ++p)
        reinterpret_cast<int4*>(segL)[t + p * 256] =
            reinterpret_cast<const int4*>(seg + f0)[t + p * 256];

    // stage xn = x*scale, packed fp8 (32 rows x 256 cols)
    #pragma unroll
    for (int p = 0; p < 8; ++p) {
        const int row = p * 4 + (t >> 6);
        const int col = (t & 63) * 4;
        const float4 v = *reinterpret_cast<const float4*>(x + (size_t)(b0 + row) * DM + col);
        const u32 w01 = f2f8x2(v.x * scale, v.y * scale);
        const u32 w23 = f2f8x2(v.z * scale, v.w * scale);
        const int e = (((row >> 4) * 8 + (col >> 5)) * 512 + ((col >> 3) & 3) * 128 + (row & 15) * 8 + (col & 7));
        *reinterpret_cast<u32*>(&xs[e]) = w01 | (w23 << 16);
    }
    __syncthreads();
    if (t < NMACRO) {
        msegL[t] = segL[t * MACRO];
        muniL[t] = (segL[t * MACRO] == segL[t * MACRO + MACRO - 1]);
    }
    __syncthreads();

    f32x4 pacc[2][4];
    #pragma unroll
    for (int i = 0; i < 2; ++i)
        #pragma unroll
        for (int j = 0; j < 4; ++j) pacc[i][j] = (f32x4)0.0f;

    int cur = msegL[0];
    float l1a0 = 0.0f, l1a1 = 0.0f;
    int myseg = -1;
    unsigned l0c = 0u;
    const int Dg0 = 4 * w;

    auto flush = [&](int s) {
        u16* pb = pieces + (size_t)s2s[s] * (BATCH * DM);
        #pragma unroll
        for (int rt = 0; rt < 2; ++rt)
            #pragma unroll
            for (int ct = 0; ct < 4; ++ct)
                #pragma unroll
                for (int r = 0; r < 4; ++r) {
                    const int row = b0 + 16 * rt + lg * 4 + r;
                    const int col = 64 * w + 16 * ct + l15;
                    pb[(size_t)row * DM + col] = f2b(pacc[rt][ct][r] * INV_WD);
                    pacc[rt][ct][r] = 0.0f;
                }
    };

    // encode MFMAs from pre-loaded We regs
    auto encodeR = [&](f32x4 (&eacc)[2][2], u64 (&we)[2][8]) {
        #pragma unroll
        for (int kf = 0; kf < 8; ++kf) {
            u64 a[2];
            #pragma unroll
            for (int rt = 0; rt < 2; ++rt)
                a[rt] = *reinterpret_cast<const u64*>(&xs[((rt * 8 + kf) * 64 + l) * 8]);
            #pragma unroll
            for (int rt = 0; rt < 2; ++rt)
                #pragma unroll
                for (int ct = 0; ct < 2; ++ct)
                    eacc[rt][ct] = mfma8(a[rt], we[ct][kf], eacc[rt][ct]);
        }
    };

    // epilogue: bias (unscale We), relu, l1 (batched log), l0, acts -> buf[it&1]
    auto epilogue = [&](int it, f32x4 (&eacc)[2][2], const float* biasv, const float* wdnv) {
        const bool uni = (muniL[it] != 0);
        unsigned char* ab = acts + (it & 1) * ACTS_SZ;
        const int fbl = it * MACRO;
        #pragma unroll
        for (int ct = 0; ct < 2; ++ct) {
            const int s = uni ? msegL[it] : segL[fbl + 32 * w + 16 * ct + l15];
            if (s != myseg) {
                if (myseg >= 0) atomicAdd(&lds_l1[myseg], l1a0 + l1a1);
                l1a0 = 0.0f; l1a1 = 0.0f; myseg = s;
            }
            #pragma unroll
            for (int rt = 0; rt < 2; ++rt) {
                float av[4];
                float prod = 1.0f;
                #pragma unroll
                for (int r = 0; r < 4; ++r) {
                    float a = fmaf(eacc[rt][ct][r], INV_WE, biasv[ct]);
                    a = fmaxf(a, 0.0f);
                    l0c += (unsigned)__popcll(__ballot(a > 0.0f));
                    prod *= fmaf(a, wdnv[ct], 1.0f);   // v in [1,~50]; prod<=~6e6
                    av[r] = a;
                }
                if (rt == 0) l1a0 += __logf(prod);      // sum(log v) = log(prod v)
                else         l1a1 += __logf(prod);
                const u32 p01 = f2f8x2(av[0], av[1]);
                const u32 p23 = f2f8x2(av[2], av[3]);
                const int e0 = (rt * 4 + w) * 512 + (2 * ct + (l15 >> 3)) * 128 + (lg * 4) * 8 + (l15 & 7);
                ab[e0]      = (unsigned char)(p01 & 0xFF);
                ab[e0 + 8]  = (unsigned char)((p01 >> 8) & 0xFF);
                ab[e0 + 16] = (unsigned char)(p23 & 0xFF);
                ab[e0 + 24] = (unsigned char)((p23 >> 8) & 0xFF);
            }
        }
    };

    // decode macro ms from acts buf[ms&1], B from pre-loaded regs
    auto decodeR = [&](int ms, u64 (&wdv)[4][4]) {
        const unsigned char* ab = acts + (ms & 1) * ACTS_SZ;
        if (muniL[ms]) {
            const int s = msegL[ms];
            if (s != cur) { flush(cur); cur = s; }
            #pragma unroll
            for (int kf = 0; kf < 4; ++kf) {
                u64 a[2];
                #pragma unroll
                for (int rt = 0; rt < 2; ++rt)
                    a[rt] = *reinterpret_cast<const u64*>(&ab[((rt * 4 + kf) * 64 + l) * 8]);
                #pragma unroll
                for (int rt = 0; rt < 2; ++rt)
                    #pragma unroll
                    for (int ct = 0; ct < 4; ++ct)
                        pacc[rt][ct] = mfma8(a[rt], wdv[ct][kf], pacc[rt][ct]);
            }
        } else {
            const int fbl = ms * MACRO;
            #pragma unroll
            for (int kf = 0; kf < 4; ++kf) {
                const int W0 = fbl + kf * 32;
                const int s0 = segL[W0], s1 = segL[W0 + 31];
                if (s0 == s1) {
                    if (s0 != cur) { flush(cur); cur = s0; }
                    u64 a[2];
                    #pragma unroll
                    for (int rt = 0; rt < 2; ++rt)
                        a[rt] = *reinterpret_cast<const u64*>(&ab[((rt * 4 + kf) * 64 + l) * 8]);
                    #pragma unroll
                    for (int rt = 0; rt < 2; ++rt)
                        #pragma unroll
                        for (int ct = 0; ct < 4; ++ct)
                            pacc[rt][ct] = mfma8(a[rt], wdv[ct][kf], pacc[rt][ct]);
                } else {
                    int lo = 0;
                    while (lo < 32) {
                        const int s = segL[W0 + lo];
                        int hi = lo + 1;
                        while (hi < 32 && segL[W0 + hi] == s) ++hi;
                        if (s != cur) { flush(cur); cur = s; }
                        // byte-mask this lane's k-range [lo,hi): lane covers lg*8..lg*8+8
                        const int loB = min(max(lo - lg * 8, 0), 8);
                        const int hiB = min(max(hi - lg * 8, 0), 8);
                        const int n = hiB - loB;
                        u64 mask = 0;
                        if (n >= 8) mask = ~0ull;
                        else if (n > 0) mask = ((1ull << (n * 8)) - 1ull) << (loB * 8);
                        #pragma unroll
                        for (int rt = 0; rt < 2; ++rt) {
                            const u64 a = (*reinterpret_cast<const u64*>(&ab[((rt * 4 + kf) * 64 + l) * 8])) & mask;
                            #pragma unroll
                            for (int ct = 0; ct < 4; ++ct)
                                pacc[rt][ct] = mfma8(a, wdv[ct][kf], pacc[rt][ct]);
                        }
                        lo = hi;
                    }
                }
            }
        }
    };

    // ---- prologue: encode(0) + epilogue(0) ----
    {
        u64 we[2][8];
        const int F0 = (f0 >> 4) + 2 * w;
        #pragma unroll
        for (int kf = 0; kf < 8; ++kf)
            #pragma unroll
            for (int ct = 0; ct < 2; ++ct)
                we[ct][kf] = *reinterpret_cast<const u64*>(WeP + (((size_t)(F0 + ct) * 8 + kf) * 64 + l) * 8);
        float biasv[2], wdnv[2];
        #pragma unroll
        for (int ct = 0; ct < 2; ++ct) {
            const int fg = f0 + 32 * w + 16 * ct + l15;
            biasv[ct] = be[fg];
            wdnv[ct] = ws[WS_WDN + fg] * 10.0f;
        }
        f32x4 eacc[2][2];
        #pragma unroll
        for (int i = 0; i < 2; ++i)
            #pragma unroll
            for (int j = 0; j < 2; ++j) eacc[i][j] = (f32x4)0.0f;
        encodeR(eacc, we);
        epilogue(0, eacc, biasv, wdnv);
    }

    // ---- pipelined main loop: encode(it) || decode(it-1) ----
    for (int it = 1; it <= NMACRO; ++it) {
        RAW_BARRIER();   // acts buf[(it-1)&1] visible; prior reads of buf[it&1] done
        const int itm1 = it - 1;

        if (it < NMACRO) {
            // branchless load burst: We(it) then Wd(it-1) then scalars
            u64 we[2][8];
            const int F0 = ((f0 + it * MACRO) >> 4) + 2 * w;
            #pragma unroll
            for (int kf = 0; kf < 8; ++kf)
                #pragma unroll
                for (int ct = 0; ct < 2; ++ct)
                    we[ct][kf] = *reinterpret_cast<const u64*>(WeP + (((size_t)(F0 + ct) * 8 + kf) * 64 + l) * 8);
            u64 wdv[4][4];
            const int G0 = (f0 + itm1 * MACRO) >> 5;
            #pragma unroll
            for (int kf = 0; kf < 4; ++kf)
                #pragma unroll
                for (int ct = 0; ct < 4; ++ct)
                    wdv[ct][kf] = *reinterpret_cast<const u64*>(WdP + (((size_t)(Dg0 + ct) * 1024 + G0 + kf) * 64 + l) * 8);
            float biasv[2], wdnv[2];
            #pragma unroll
            for (int ct = 0; ct < 2; ++ct) {
                const int fg = f0 + it * MACRO + 32 * w + 16 * ct + l15;
                biasv[ct] = be[fg];
                wdnv[ct] = ws[WS_WDN + fg] * 10.0f;
            }

            f32x4 eacc[2][2];
            #pragma unroll
            for (int i = 0; i < 2; ++i)
                #pragma unroll
                for (int j = 0; j < 2; ++j) eacc[i][j] = (f32x4)0.0f;
            encodeR(eacc, we);          // consumes earliest burst loads
            decodeR(itm1, wdv);         // wd landed during encode
            epilogue(it, eacc, biasv, wdnv);
        } else {
            // drain: decode(NMACRO-1) only
            u64 wdv[4][4];
            const int G0 = (f0 + itm1 * MACRO) >> 5;
            #pragma unroll
            for (int kf = 0; kf < 4; ++kf)
                #pragma unroll
                for (int ct = 0; ct < 4; ++ct)
                    wdv[ct][kf] = *reinterpret_cast<const u64*>(WdP + (((size_t)(Dg0 + ct) * 1024 + G0 + kf) * 64 + l) * 8);
            decodeR(itm1, wdv);
        }
    }

    flush(cur);
    if (myseg >= 0) atomicAdd(&lds_l1[myseg], l1a0 + l1a1);
    if (l == 0) atomicAdd(&lds_l0, l0c);    // l0c wave-uniform (ballot)
    __syncthreads();
    if (t < NBLK) atomicAdd(&ws[WS_L1 + t], lds_l1[t]);
    if (t == 0) atomicAdd(((unsigned*)ws) + WS_L0, lds_l0);
}

// ---------------- epilogue kernels ----------------

__global__ __launch_bounds__(256) void k_err(const float* __restrict__ x,
                                             const float* __restrict__ bd,
                                             float* ws,
                                             const u16* __restrict__ pieces) {
    const int b = blockIdx.x, t = threadIdx.x;
    const int wave = t >> 6, lane = t & 63;
    const int* wsi = (const int*)ws;
    const int N = wsi[WSI_PTN];
    const float scale = ws[WS_SCALE];
    const float xv = x[(size_t)b * DM + t] * scale;
    float p = bd[t];
    __shared__ float lds[NBLK][4];
    for (int i = 0; i < N; ++i) {
        p += b2f(pieces[(size_t)i * (BATCH * DM) + (size_t)b * DM + t]);
        const int sg = wsi[WSI_PSEG + i];
        const bool end = (i == N - 1) || (wsi[WSI_PSEG + i + 1] != sg);
        if (end) {
            const float d = p - xv;
            float e = d * d;
            #pragma unroll
            for (int o = 32; o; o >>= 1) e += __shfl_xor(e, o);
            if (lane == 0) lds[sg][wave] = e;
        }
    }
    __syncthreads();
    if (t < NBLK) {
        const float s = lds[t][0] + lds[t][1] + lds[t][2] + lds[t][3];
        atomicAdd(&ws[WS_ERR + t], s);
    }
}

__global__ void k_loss(const float* __restrict__ bw,
                       const float* __restrict__ l1s,
                       const float* ws, float* out) {
    float cum = 0.0f, l1 = 0.0f, mse = 0.0f;
    for (int k = 0; k < NBLK; ++k) {
        cum += ws[WS_L1 + k] / (float)BATCH;
        l1 += bw[k] * cum;
        mse += bw[k] * (ws[WS_ERR + k] / (float)BATCH);
    }
    l1 *= (1.0f / NBLK);
    mse *= (1.0f / NBLK);
    const unsigned l0 = ((const unsigned*)ws)[WS_L0];
    const float avg_l0 = (float)l0 / (float)BATCH;
    const float rs = l1s[0] * (avg_l0 < TARGET_L0 ? (1.0f - EPS_CTRL) : (1.0f + EPS_CTRL));
    out[0] = mse + rs * l1;
}

// ---------------- launch ----------------

extern "C" void kernel_launch(void* const* d_in, const int* in_sizes, int n_in,
                              void* d_out, int out_size, void* d_ws, size_t ws_size,
                              hipStream_t stream) {
    const float* x    = (const float*)d_in[0];
    const float* We   = (const float*)d_in[1];
    const float* be   = (const float*)d_in[2];
    const float* Wd   = (const float*)d_in[3];
    const float* bd   = (const float*)d_in[4];
    const float* bw   = (const float*)d_in[5];
    const float* ravg = (const float*)d_in[6];
    const float* l1s  = (const float*)d_in[7];
    const int*   seg  = (const int*)d_in[8];
    float* out = (float*)d_out;
    float* ws  = (float*)d_ws;
    u16* pieces = (u16*)((char*)d_ws + PIECES_OFF_BYTES);
    unsigned char* WeP = (unsigned char*)d_ws + WEP_OFF_BYTES;
    unsigned char* WdP = (unsigned char*)d_ws + WDP_OFF_BYTES;

    hipMemsetAsync(d_ws, 0, 1024, stream);           // zero accumulators only
    k_pack<<<2048 + BATCH / 4 + NFEAT / 256, 256, 0, stream>>>(We, Wd, x, seg, WeP, WdP, ws);
    k_pt2<<<1, 64, 0, stream>>>(seg, ravg, ws);
    dim3 g(NFEAT / FC, BATCH / BT);   // chunk-fast -> XCD = chunk%8 (L2-fit weights)
    k_main<<<g, 256, 0, stream>>>(x, be, seg, ws, pieces, WeP, WdP);
    k_err<<<BATCH, 256, 0, stream>>>(x, bd, ws, pieces);
    k_loss<<<1, 1, 0, stream>>>(bw, l1s, ws, out);
}

// Round 26
// 197.811 us; speedup vs baseline: 1.0516x; 1.0162x over previous
//
#include <hip/hip_runtime.h>
#include <hip/hip_fp8.h>

typedef float  f32x4  __attribute__((ext_vector_type(4)));
typedef unsigned short u16;
typedef unsigned int   u32;
typedef unsigned long long u64;

#define BATCH 2048
#define DM    256
#define NFEAT 32768
#define NBLK  8
#define ALPHA_C   0.99f
#define EPS_CTRL  3e-4f
#define TARGET_L0 100.0f

#define BT    32          // batch rows per workgroup
#define FC    2048        // features per chunk
#define NCHUNK (NFEAT / FC)
#define MACRO 128         // features per macro-iter
#define NMACRO (FC / MACRO)
#define NPMAX 24          // max pieces = 16 chunks + 7 seg boundaries
#define ACTS_SZ (BT * MACRO)   // bytes (fp8)

// fp8 pre-scales (keep weights in e4m3 normal range; unscale after MFMA)
#define SCL_WE 8.0f
#define INV_WE 0.125f
#define SCL_WD 16.0f
#define INV_WD 0.0625f

// ---- workspace layout ----
#define WS_RA    0
#define WS_SCALE 1
#define WS_L0    2      // as unsigned
#define WS_L1    4      // 8 floats
#define WS_ERR   16     // 8 floats
#define WSI_BND  32     // 8 ints
#define WSI_PTN  40
#define WSI_PTS  41
#define WSI_PSEG 66
#define WS_WDN   256    // 32768 floats
#define PIECES_OFF_BYTES ((size_t)262144)                         // 256 KB
#define PIECES_BYTES ((size_t)NPMAX * BATCH * DM * 2)             // 24 MB bf16
#define WEP_OFF_BYTES (PIECES_OFF_BYTES + PIECES_BYTES)           // fp8 We, 8 MB
#define WDP_OFF_BYTES (WEP_OFF_BYTES + (size_t)NFEAT * DM)        // fp8 Wd, 8 MB

// lgkm-only barrier (protects LDS only; global loads ride across)
#define RAW_BARRIER() asm volatile("s_waitcnt lgkmcnt(0)\n\ts_barrier" ::: "memory")

static __device__ inline u16 f2b(float f) {
    return __builtin_bit_cast(u16, (__bf16)f);
}
static __device__ inline float b2f(u16 u) {
    return (float)__builtin_bit_cast(__bf16, u);
}
// pack 2 f32 -> 2 fp8(e4m3) in low 16 bits
static __device__ inline u32 f2f8x2(float a, float b) {
#if __has_builtin(__builtin_amdgcn_cvt_pk_fp8_f32)
    return ((u32)__builtin_amdgcn_cvt_pk_fp8_f32(a, b, 0, false)) & 0xFFFFu;
#else
    __hip_fp8_e4m3 ha(a), hb(b);
    return (u32)(*reinterpret_cast<unsigned char*>(&ha)) |
           ((u32)(*reinterpret_cast<unsigned char*>(&hb)) << 8);
#endif
}
static __device__ inline f32x4 mfma8(u64 a, u64 b, f32x4 c) {
    return __builtin_amdgcn_mfma_f32_16x16x32_fp8_fp8((long)a, (long)b, c, 0, 0, 0);
}

// ---------------- merged prep+pack kernel ----------------
// bid < 1024: We fp8 pack slab; bid < 2048: Wd fp8 pack slab + fused wdn;
// bid < 2048+512: x rownorm; else: seg boundary detect.
__global__ __launch_bounds__(256) void k_pack(const float* __restrict__ We,
                                              const float* __restrict__ Wd,
                                              const float* __restrict__ x,
                                              const int* __restrict__ seg,
                                              unsigned char* __restrict__ WeP,
                                              unsigned char* __restrict__ WdP,
                                              float* ws) {
    __shared__ float tile[32][261];   // pitch 261: spreads gather banks
    const int t = threadIdx.x;
    const int bid = blockIdx.x;
    if (bid < 1024) {
        const int kf = bid & 7, fblk = bid >> 3;
        const int f0 = fblk * 256;
        #pragma unroll
        for (int p = 0; p < 8; ++p) {
            const int r = p * 4 + (t >> 6);
            const int c = (t & 63) * 4;
            const float4 v = *reinterpret_cast<const float4*>(We + (size_t)(kf * 32 + r) * NFEAT + f0 + c);
            tile[r][c] = v.x; tile[r][c + 1] = v.y; tile[r][c + 2] = v.z; tile[r][c + 3] = v.w;
        }
        __syncthreads();
        #pragma unroll
        for (int p = 0; p < 4; ++p) {
            const int item = p * 256 + t;
            const int g = item >> 6, l = item & 63;
            const int F = fblk * 16 + g;
            float tv[8];
            #pragma unroll
            for (int i = 0; i < 8; ++i)
                tv[i] = tile[(l >> 4) * 8 + i][g * 16 + (l & 15)] * SCL_WE;
            const u32 lo = f2f8x2(tv[0], tv[1]) | (f2f8x2(tv[2], tv[3]) << 16);
            const u32 hi = f2f8x2(tv[4], tv[5]) | (f2f8x2(tv[6], tv[7]) << 16);
            *reinterpret_cast<u64*>(WeP + ((size_t)(F * 8 + kf) * 64 + l) * 8) = (u64)lo | ((u64)hi << 32);
        }
    } else if (bid < 2048) {
        const int G = bid - 1024;
        #pragma unroll
        for (int p = 0; p < 8; ++p) {
            const int r = p * 4 + (t >> 6);
            const int c = (t & 63) * 4;
            const float4 v = *reinterpret_cast<const float4*>(Wd + (size_t)(G * 32 + r) * DM + c);
            tile[r][c] = v.x; tile[r][c + 1] = v.y; tile[r][c + 2] = v.z; tile[r][c + 3] = v.w;
        }
        __syncthreads();
        // fused wdn (from f32 tile — unaffected by fp8 scaling)
        {
            const int row = t >> 3, part = t & 7;
            float s = 0.0f;
            #pragma unroll
            for (int j = 0; j < 32; ++j) {
                const float xv = tile[row][part * 32 + j];
                s += xv * xv;
            }
            s += __shfl_xor(s, 1); s += __shfl_xor(s, 2); s += __shfl_xor(s, 4);
            if (part == 0) ws[WS_WDN + G * 32 + row] = sqrtf(s);
        }
        #pragma unroll
        for (int p = 0; p < 4; ++p) {
            const int item = p * 256 + t;
            const int g = item >> 6, l = item & 63;
            float tv[8];
            #pragma unroll
            for (int i = 0; i < 8; ++i)
                tv[i] = tile[(l >> 4) * 8 + i][g * 16 + (l & 15)] * SCL_WD;
            const u32 lo = f2f8x2(tv[0], tv[1]) | (f2f8x2(tv[2], tv[3]) << 16);
            const u32 hi = f2f8x2(tv[4], tv[5]) | (f2f8x2(tv[6], tv[7]) << 16);
            *reinterpret_cast<u64*>(WdP + ((size_t)(g * 1024 + G) * 64 + l) * 8) = (u64)lo | ((u64)hi << 32);
        }
    } else if (bid < 2048 + BATCH / 4) {
        // x rownorm
        const int wave = t >> 6, lane = t & 63;
        const int row = (bid - 2048) * 4 + wave;
        const float4 v = *reinterpret_cast<const float4*>(x + (size_t)row * DM + lane * 4);
        float s = v.x * v.x + v.y * v.y + v.z * v.z + v.w * v.w;
        #pragma unroll
        for (int o = 32; o; o >>= 1) s += __shfl_xor(s, o);
        if (lane == 0) atomicAdd(&ws[WS_RA], sqrtf(s));
    } else {
        // seg boundaries
        const int f = (bid - 2048 - BATCH / 4) * 256 + t;
        if (f > 0 && f < NFEAT) {
            const int s = seg[f];
            if (s != seg[f - 1]) ((int*)ws)[WSI_BND + s] = f;
        }
    }
}

// piece table + normalizer scale; 64 threads
__global__ void k_pt2(const int* __restrict__ seg,
                      const float* __restrict__ ravg, float* ws) {
    __shared__ int stv[NCHUNK + NBLK];
    __shared__ int outL[NPMAX];
    __shared__ int NL;
    int* wsi = (int*)ws;
    const int t = threadIdx.x;
    if (t < NCHUNK) stv[t] = t * FC;
    else if (t < NCHUNK + NBLK - 1) stv[t] = wsi[WSI_BND + (t - NCHUNK + 1)];
    __syncthreads();
    if (t == 0) {
        int i = 0, j = NCHUNK, N = 0;
        while (i < NCHUNK || j < NCHUNK + NBLK - 1) {
            int v;
            if (i < NCHUNK && (j >= NCHUNK + NBLK - 1 || stv[i] <= stv[j])) v = stv[i++];
            else v = stv[j++];
            if (N == 0 || outL[N - 1] != v) outL[N++] = v;
        }
        NL = N;
    }
    __syncthreads();
    const int N = NL;
    if (t < N) {
        wsi[WSI_PTS + t] = outL[t];
        wsi[WSI_PSEG + t] = seg[outL[t]];
    }
    if (t == 0) {
        wsi[WSI_PTN] = N;
        wsi[WSI_PTS + N] = NFEAT;
        float ra = ALPHA_C * ravg[0] + (1.0f - ALPHA_C) * (ws[WS_RA] / (float)BATCH);
        ws[WS_SCALE] = 16.0f / ra;   // sqrt(256) = 16
    }
}

// ---------------- fused main kernel: r25 optimum + 8-wide batched log ----------------
// 256 threads = 4 waves, BT=32, MACRO=128. SINGLE CHANGE vs the verified
// 135us build: per ct, the two rt 4-products combine into one 8-product
// (same feature -> same segment/wdn), so 4 logf/macro -> 2. prod <= ~50^8
// = 3.9e13, f32-safe. Single l1 accumulator (2 logf can't bottleneck).
__global__ __launch_bounds__(256, 2) void k_main(const float* __restrict__ x,
                                                 const float* __restrict__ be,
                                                 const int* __restrict__ seg,
                                                 float* __restrict__ ws,
                                                 u16* __restrict__ pieces,
                                                 const unsigned char* __restrict__ WeP,
                                                 const unsigned char* __restrict__ WdP) {
    __shared__ __align__(16) unsigned char xs[BT * DM];        // 8 KB fp8 packed
    __shared__ __align__(16) unsigned char acts[2 * ACTS_SZ];  // 8 KB dbuf fp8
    __shared__ int segL[FC];                                   // 8 KB
    __shared__ float lds_l1[NBLK];
    __shared__ unsigned lds_l0;
    __shared__ int s2s[NBLK];
    __shared__ int msegL[NMACRO];
    __shared__ int muniL[NMACRO];

    const int t = threadIdx.x;
    const int w = t >> 6;           // 0..3
    const int l = t & 63;
    const int l15 = l & 15, lg = l >> 4;
    const int f0 = blockIdx.x * FC;
    const int b0 = blockIdx.y * BT;
    const float scale = ws[WS_SCALE];
    const int* wsi = (const int*)ws;

    if (t < NBLK) lds_l1[t] = 0.0f;
    if (t == 0) lds_l0 = 0u;
    if (t < NPMAX) {
        const int N = wsi[WSI_PTN];
        if (t < N) {
            const int ps = wsi[WSI_PTS + t];
            if (ps >= f0 && ps < f0 + FC) s2s[wsi[WSI_PSEG + t]] = t;
        }
    }

    // stage seg chunk
    #pragma unroll
    for (int p = 0; p < 2; ++p)
        reinterpret_cast<int4*>(segL)[t + p * 256] =
            reinterpret_cast<const int4*>(seg + f0)[t + p * 256];

    // stage xn = x*scale, packed fp8 (32 rows x 256 cols)
    #pragma unroll
    for (int p = 0; p < 8; ++p) {
        const int row = p * 4 + (t >> 6);
        const int col = (t & 63) * 4;
        const float4 v = *reinterpret_cast<const float4*>(x + (size_t)(b0 + row) * DM + col);
        const u32 w01 = f2f8x2(v.x * scale, v.y * scale);
        const u32 w23 = f2f8x2(v.z * scale, v.w * scale);
        const int e = (((row >> 4) * 8 + (col >> 5)) * 512 + ((col >> 3) & 3) * 128 + (row & 15) * 8 + (col & 7));
        *reinterpret_cast<u32*>(&xs[e]) = w01 | (w23 << 16);
    }
    __syncthreads();
    if (t < NMACRO) {
        msegL[t] = segL[t * MACRO];
        muniL[t] = (segL[t * MACRO] == segL[t * MACRO + MACRO - 1]);
    }
    __syncthreads();

    f32x4 pacc[2][4];
    #pragma unroll
    for (int i = 0; i < 2; ++i)
        #pragma unroll
        for (int j = 0; j < 4; ++j) pacc[i][j] = (f32x4)0.0f;

    int cur = msegL[0];
    float l1a = 0.0f;
    int myseg = -1;
    unsigned l0c = 0u;
    const int Dg0 = 4 * w;

    auto flush = [&](int s) {
        u16* pb = pieces + (size_t)s2s[s] * (BATCH * DM);
        #pragma unroll
        for (int rt = 0; rt < 2; ++rt)
            #pragma unroll
            for (int ct = 0; ct < 4; ++ct)
                #pragma unroll
                for (int r = 0; r < 4; ++r) {
                    const int row = b0 + 16 * rt + lg * 4 + r;
                    const int col = 64 * w + 16 * ct + l15;
                    pb[(size_t)row * DM + col] = f2b(pacc[rt][ct][r] * INV_WD);
                    pacc[rt][ct][r] = 0.0f;
                }
    };

    // encode MFMAs from pre-loaded We regs
    auto encodeR = [&](f32x4 (&eacc)[2][2], u64 (&we)[2][8]) {
        #pragma unroll
        for (int kf = 0; kf < 8; ++kf) {
            u64 a[2];
            #pragma unroll
            for (int rt = 0; rt < 2; ++rt)
                a[rt] = *reinterpret_cast<const u64*>(&xs[((rt * 8 + kf) * 64 + l) * 8]);
            #pragma unroll
            for (int rt = 0; rt < 2; ++rt)
                #pragma unroll
                for (int ct = 0; ct < 2; ++ct)
                    eacc[rt][ct] = mfma8(a[rt], we[ct][kf], eacc[rt][ct]);
        }
    };

    // epilogue: bias (unscale We), relu, l1 (8-wide batched log), l0, acts
    auto epilogue = [&](int it, f32x4 (&eacc)[2][2], const float* biasv, const float* wdnv) {
        const bool uni = (muniL[it] != 0);
        unsigned char* ab = acts + (it & 1) * ACTS_SZ;
        const int fbl = it * MACRO;
        #pragma unroll
        for (int ct = 0; ct < 2; ++ct) {
            const int s = uni ? msegL[it] : segL[fbl + 32 * w + 16 * ct + l15];
            if (s != myseg) {
                if (myseg >= 0) atomicAdd(&lds_l1[myseg], l1a);
                l1a = 0.0f; myseg = s;
            }
            float prod = 1.0f;   // 8 values, same feature -> same segment/wdn
            #pragma unroll
            for (int rt = 0; rt < 2; ++rt) {
                float av[4];
                #pragma unroll
                for (int r = 0; r < 4; ++r) {
                    float a = fmaf(eacc[rt][ct][r], INV_WE, biasv[ct]);
                    a = fmaxf(a, 0.0f);
                    l0c += (unsigned)__popcll(__ballot(a > 0.0f));
                    prod *= fmaf(a, wdnv[ct], 1.0f);   // v in [1,~50]; prod<=~4e13
                    av[r] = a;
                }
                const u32 p01 = f2f8x2(av[0], av[1]);
                const u32 p23 = f2f8x2(av[2], av[3]);
                const int e0 = (rt * 4 + w) * 512 + (2 * ct + (l15 >> 3)) * 128 + (lg * 4) * 8 + (l15 & 7);
                ab[e0]      = (unsigned char)(p01 & 0xFF);
                ab[e0 + 8]  = (unsigned char)((p01 >> 8) & 0xFF);
                ab[e0 + 16] = (unsigned char)(p23 & 0xFF);
                ab[e0 + 24] = (unsigned char)((p23 >> 8) & 0xFF);
            }
            l1a += __logf(prod);      // sum(log v) = log(prod v), 8-wide
        }
    };

    // decode macro ms from acts buf[ms&1], B from pre-loaded regs
    auto decodeR = [&](int ms, u64 (&wdv)[4][4]) {
        const unsigned char* ab = acts + (ms & 1) * ACTS_SZ;
        if (muniL[ms]) {
            const int s = msegL[ms];
            if (s != cur) { flush(cur); cur = s; }
            #pragma unroll
            for (int kf = 0; kf < 4; ++kf) {
                u64 a[2];
                #pragma unroll
                for (int rt = 0; rt < 2; ++rt)
                    a[rt] = *reinterpret_cast<const u64*>(&ab[((rt * 4 + kf) * 64 + l) * 8]);
                #pragma unroll
                for (int rt = 0; rt < 2; ++rt)
                    #pragma unroll
                    for (int ct = 0; ct < 4; ++ct)
                        pacc[rt][ct] = mfma8(a[rt], wdv[ct][kf], pacc[rt][ct]);
            }
        } else {
            const int fbl = ms * MACRO;
            #pragma unroll
            for (int kf = 0; kf < 4; ++kf) {
                const int W0 = fbl + kf * 32;
                const int s0 = segL[W0], s1 = segL[W0 + 31];
                if (s0 == s1) {
                    if (s0 != cur) { flush(cur); cur = s0; }
                    u64 a[2];
                    #pragma unroll
                    for (int rt = 0; rt < 2; ++rt)
                        a[rt] = *reinterpret_cast<const u64*>(&ab[((rt * 4 + kf) * 64 + l) * 8]);
                    #pragma unroll
                    for (int rt = 0; rt < 2; ++rt)
                        #pragma unroll
                        for (int ct = 0; ct < 4; ++ct)
                            pacc[rt][ct] = mfma8(a[rt], wdv[ct][kf], pacc[rt][ct]);
                } else {
                    int lo = 0;
                    while (lo < 32) {
                        const int s = segL[W0 + lo];
                        int hi = lo + 1;
                        while (hi < 32 && segL[W0 + hi] == s) ++hi;
                        if (s != cur) { flush(cur); cur = s; }
                        // byte-mask this lane's k-range [lo,hi): lane covers lg*8..lg*8+8
                        const int loB = min(max(lo - lg * 8, 0), 8);
                        const int hiB = min(max(hi - lg * 8, 0), 8);
                        const int n = hiB - loB;
                        u64 mask = 0;
                        if (n >= 8) mask = ~0ull;
                        else if (n > 0) mask = ((1ull << (n * 8)) - 1ull) << (loB * 8);
                        #pragma unroll
                        for (int rt = 0; rt < 2; ++rt) {
                            const u64 a = (*reinterpret_cast<const u64*>(&ab[((rt * 4 + kf) * 64 + l) * 8])) & mask;
                            #pragma unroll
                            for (int ct = 0; ct < 4; ++ct)
                                pacc[rt][ct] = mfma8(a, wdv[ct][kf], pacc[rt][ct]);
                        }
                        lo = hi;
                    }
                }
            }
        }
    };

    // ---- prologue: encode(0) + epilogue(0) ----
    {
        u64 we[2][8];
        const int F0 = (f0 >> 4) + 2 * w;
        #pragma unroll
        for (int kf = 0; kf < 8; ++kf)
            #pragma unroll
            for (int ct = 0; ct < 2; ++ct)
                we[ct][kf] = *reinterpret_cast<const u64*>(WeP + (((size_t)(F0 + ct) * 8 + kf) * 64 + l) * 8);
        float biasv[2], wdnv[2];
        #pragma unroll
        for (int ct = 0; ct < 2; ++ct) {
            const int fg = f0 + 32 * w + 16 * ct + l15;
            biasv[ct] = be[fg];
            wdnv[ct] = ws[WS_WDN + fg] * 10.0f;
        }
        f32x4 eacc[2][2];
        #pragma unroll
        for (int i = 0; i < 2; ++i)
            #pragma unroll
            for (int j = 0; j < 2; ++j) eacc[i][j] = (f32x4)0.0f;
        encodeR(eacc, we);
        epilogue(0, eacc, biasv, wdnv);
    }

    // ---- pipelined main loop: encode(it) || decode(it-1) ----
    for (int it = 1; it <= NMACRO; ++it) {
        RAW_BARRIER();   // acts buf[(it-1)&1] visible; prior reads of buf[it&1] done
        const int itm1 = it - 1;

        if (it < NMACRO) {
            // branchless load burst: We(it) then Wd(it-1) then scalars
            u64 we[2][8];
            const int F0 = ((f0 + it * MACRO) >> 4) + 2 * w;
            #pragma unroll
            for (int kf = 0; kf < 8; ++kf)
                #pragma unroll
                for (int ct = 0; ct < 2; ++ct)
                    we[ct][kf] = *reinterpret_cast<const u64*>(WeP + (((size_t)(F0 + ct) * 8 + kf) * 64 + l) * 8);
            u64 wdv[4][4];
            const int G0 = (f0 + itm1 * MACRO) >> 5;
            #pragma unroll
            for (int kf = 0; kf < 4; ++kf)
                #pragma unroll
                for (int ct = 0; ct < 4; ++ct)
                    wdv[ct][kf] = *reinterpret_cast<const u64*>(WdP + (((size_t)(Dg0 + ct) * 1024 + G0 + kf) * 64 + l) * 8);
            float biasv[2], wdnv[2];
            #pragma unroll
            for (int ct = 0; ct < 2; ++ct) {
                const int fg = f0 + it * MACRO + 32 * w + 16 * ct + l15;
                biasv[ct] = be[fg];
                wdnv[ct] = ws[WS_WDN + fg] * 10.0f;
            }

            f32x4 eacc[2][2];
            #pragma unroll
            for (int i = 0; i < 2; ++i)
                #pragma unroll
                for (int j = 0; j < 2; ++j) eacc[i][j] = (f32x4)0.0f;
            encodeR(eacc, we);          // consumes earliest burst loads
            decodeR(itm1, wdv);         // wd landed during encode
            epilogue(it, eacc, biasv, wdnv);
        } else {
            // drain: decode(NMACRO-1) only
            u64 wdv[4][4];
            const int G0 = (f0 + itm1 * MACRO) >> 5;
            #pragma unroll
            for (int kf = 0; kf < 4; ++kf)
                #pragma unroll
                for (int ct = 0; ct < 4; ++ct)
                    wdv[ct][kf] = *reinterpret_cast<const u64*>(WdP + (((size_t)(Dg0 + ct) * 1024 + G0 + kf) * 64 + l) * 8);
            decodeR(itm1, wdv);
        }
    }

    flush(cur);
    if (myseg >= 0) atomicAdd(&lds_l1[myseg], l1a);
    if (l == 0) atomicAdd(&lds_l0, l0c);    // l0c wave-uniform (ballot)
    __syncthreads();
    if (t < NBLK) atomicAdd(&ws[WS_L1 + t], lds_l1[t]);
    if (t == 0) atomicAdd(((unsigned*)ws) + WS_L0, lds_l0);
}

// ---------------- epilogue kernels ----------------

__global__ __launch_bounds__(256) void k_err(const float* __restrict__ x,
                                             const float* __restrict__ bd,
                                             float* ws,
                                             const u16* __restrict__ pieces) {
    const int b = blockIdx.x, t = threadIdx.x;
    const int wave = t >> 6, lane = t & 63;
    const int* wsi = (const int*)ws;
    const int N = wsi[WSI_PTN];
    const float scale = ws[WS_SCALE];
    const float xv = x[(size_t)b * DM + t] * scale;
    float p = bd[t];
    __shared__ float lds[NBLK][4];
    for (int i = 0; i < N; ++i) {
        p += b2f(pieces[(size_t)i * (BATCH * DM) + (size_t)b * DM + t]);
        const int sg = wsi[WSI_PSEG + i];
        const bool end = (i == N - 1) || (wsi[WSI_PSEG + i + 1] != sg);
        if (end) {
            const float d = p - xv;
            float e = d * d;
            #pragma unroll
            for (int o = 32; o; o >>= 1) e += __shfl_xor(e, o);
            if (lane == 0) lds[sg][wave] = e;
        }
    }
    __syncthreads();
    if (t < NBLK) {
        const float s = lds[t][0] + lds[t][1] + lds[t][2] + lds[t][3];
        atomicAdd(&ws[WS_ERR + t], s);
    }
}

__global__ void k_loss(const float* __restrict__ bw,
                       const float* __restrict__ l1s,
                       const float* ws, float* out) {
    float cum = 0.0f, l1 = 0.0f, mse = 0.0f;
    for (int k = 0; k < NBLK; ++k) {
        cum += ws[WS_L1 + k] / (float)BATCH;
        l1 += bw[k] * cum;
        mse += bw[k] * (ws[WS_ERR + k] / (float)BATCH);
    }
    l1 *= (1.0f / NBLK);
    mse *= (1.0f / NBLK);
    const unsigned l0 = ((const unsigned*)ws)[WS_L0];
    const float avg_l0 = (float)l0 / (float)BATCH;
    const float rs = l1s[0] * (avg_l0 < TARGET_L0 ? (1.0f - EPS_CTRL) : (1.0f + EPS_CTRL));
    out[0] = mse + rs * l1;
}

// ---------------- launch ----------------

extern "C" void kernel_launch(void* const* d_in, const int* in_sizes, int n_in,
                              void* d_out, int out_size, void* d_ws, size_t ws_size,
                              hipStream_t stream) {
    const float* x    = (const float*)d_in[0];
    const float* We   = (const float*)d_in[1];
    const float* be   = (const float*)d_in[2];
    const float* Wd   = (const float*)d_in[3];
    const float* bd   = (const float*)d_in[4];
    const float* bw   = (const float*)d_in[5];
    const float* ravg = (const float*)d_in[6];
    const float* l1s  = (const float*)d_in[7];
    const int*   seg  = (const int*)d_in[8];
    float* out = (float*)d_out;
    float* ws  = (float*)d_ws;
    u16* pieces = (u16*)((char*)d_ws + PIECES_OFF_BYTES);
    unsigned char* WeP = (unsigned char*)d_ws + WEP_OFF_BYTES;
    unsigned char* WdP = (unsigned char*)d_ws + WDP_OFF_BYTES;

    hipMemsetAsync(d_ws, 0, 1024, stream);           // zero accumulators only
    k_pack<<<2048 + BATCH / 4 + NFEAT / 256, 256, 0, stream>>>(We, Wd, x, seg, WeP, WdP, ws);
    k_pt2<<<1, 64, 0, stream>>>(seg, ravg, ws);
    dim3 g(NFEAT / FC, BATCH / BT);   // chunk-fast -> XCD = chunk%8 (L2-fit weights)
    k_main<<<g, 256, 0, stream>>>(x, be, seg, ws, pieces, WeP, WdP);
    k_err<<<BATCH, 256, 0, stream>>>(x, bd, ws, pieces);
    k_loss<<<1, 1, 0, stream>>>(bw, l1s, ws, out);
}